// Round 2
// baseline (92249.457 us; speedup 1.0000x reference)
//
#include <hip/hip_runtime.h>
#include <stdint.h>

#define RES    1024
#define INPD   16
#define OUTD   8
#define BATCH  32
#define SEQ    4096
#define NCMAX  20              // 20 chunks * 8 = 160 nz capacity per row
#define PASSPAD 3              // first 3 passes are exact Latin-square (padded)

// ws layout:
//   idx:  uint32 [NCMAX][1024][8]   (element index into h, 0..1023; 0 for pad)
//   val:  float  [NCMAX][1024][8]   (0.0f for pad)
//   eff:  uint32 [1024]             effective (padded) row length
//   perm: uint32 [1024]             sorted row order (desc by eff)
//   wnc:  uint32 [16]               per-wave chunk count
#define IDX_BYTES ((size_t)NCMAX * RES * 8 * 4)

// ---------------------------------------------------------------------------
// Pass 1: per-row effective length = 96 + sum_b max(cnt_bank-3, 0)
// ---------------------------------------------------------------------------
__global__ __launch_bounds__(32) void esn_count(const float* __restrict__ W,
                                                uint32_t* __restrict__ eff) {
  const int r = blockIdx.x, b = threadIdx.x;   // b = bank 0..31
  const float* row = W + (size_t)r * RES;
  int n = 0;
  for (int k = 0; k < 32; ++k) n += (row[b + 32 * k] != 0.0f) ? 1 : 0;
  int t3 = (n > PASSPAD) ? (n - PASSPAD) : 0;
  for (int o = 16; o; o >>= 1) t3 += __shfl_down(t3, o, 32);
  if (b == 0) eff[r] = (uint32_t)(PASSPAD * 32 + t3);
}

// ---------------------------------------------------------------------------
// Pass 2: bitonic sort rows by eff (descending) -> perm; per-wave chunk count
// ---------------------------------------------------------------------------
__global__ __launch_bounds__(1024) void esn_sort(const uint32_t* __restrict__ eff,
                                                 uint32_t* __restrict__ perm,
                                                 uint32_t* __restrict__ wnc) {
  __shared__ uint32_t key[RES];
  const int tid = threadIdx.x;
  key[tid] = (eff[tid] << 10) | (uint32_t)tid;
  __syncthreads();
  for (int len = 2; len <= RES; len <<= 1) {
    for (int s = len >> 1; s > 0; s >>= 1) {
      const int j = tid ^ s;
      if (j > tid) {
        const uint32_t a = key[tid], c = key[j];
        const bool up = ((tid & len) == 0);      // ascending segment
        if ((a > c) == up) { key[tid] = c; key[j] = a; }
      }
      __syncthreads();
    }
  }
  const uint32_t kd = key[(RES - 1) - tid];      // descending order
  perm[tid] = kd & 1023u;
  if ((tid & 63) == 0) {
    uint32_t mx = kd >> 10;                      // max eff in this wave's group
    uint32_t c  = (mx + 7u) >> 3;
    wnc[tid >> 6] = (c < (uint32_t)NCMAX) ? c : (uint32_t)NCMAX;
  }
}

// ---------------------------------------------------------------------------
// Pass 3: pack row perm[p] in rotated pass-major order.
//   slot s -> bank (rot + s) % 32 with rot = p % 32; passes 0..2 are exact
//   (empty slots zero-padded); tail packed with the same rotated ordering.
// ---------------------------------------------------------------------------
__global__ __launch_bounds__(32) void esn_pack(const float* __restrict__ W,
                                               const uint32_t* __restrict__ perm,
                                               uint32_t* __restrict__ idxo,
                                               float* __restrict__ valo) {
  const int p = blockIdx.x;      // sorted position == scan-kernel tid
  const int b = threadIdx.x;     // bank 0..31
  __shared__ float    vls[32][16];
  __shared__ uint16_t cls[32][16];
  __shared__ int      cnt[32];
  __shared__ uint32_t rr;
  if (b == 0) rr = perm[p];
  __syncthreads();
  const int r = (int)rr;
  const float* row = W + (size_t)r * RES;

  int n = 0;
  for (int k = 0; k < 32; ++k) {
    const float v = row[b + 32 * k];
    if (v != 0.0f && n < 16) { vls[b][n] = v; cls[b][n] = (uint16_t)(b + 32 * k); ++n; }
  }
  cnt[b] = n;
  // zero the whole capacity region for this row
  for (int e = b; e < NCMAX * 8; e += 32) {
    const size_t off = (size_t)(e >> 3) * (RES * 8) + (size_t)p * 8 + (e & 7);
    idxo[off] = 0; valo[off] = 0.0f;
  }
  __syncthreads();

  const int rot   = p & 31;
  const int myord = (b - rot) & 31;
  for (int k2 = 0; k2 < n; ++k2) {
    int rank;
    if (k2 < PASSPAD) {
      rank = k2 * 32 + myord;                    // exact Latin square
    } else {
      rank = PASSPAD * 32;
      const int kp = k2 - PASSPAD;
      for (int b2 = 0; b2 < 32; ++b2) {
        const int c2  = cnt[b2] - PASSPAD;
        const int cp  = (c2 > 0) ? c2 : 0;
        const int ord = (b2 - rot) & 31;
        const int lim = kp + ((ord < myord) ? 1 : 0);
        rank += (cp < lim) ? cp : lim;
      }
    }
    if (rank < NCMAX * 8) {
      const size_t off = (size_t)(rank >> 3) * (RES * 8) + (size_t)p * 8 + (rank & 7);
      idxo[off] = (uint32_t)cls[b][k2];
      valo[off] = vls[b][k2];
    }
  }
}

// ---------------------------------------------------------------------------
// Scan: one block per batch. Matrix resident in VGPRs; h double-buffered in
// LDS with compile-time parity (2-step unrolled loop); 1 barrier per step.
// ---------------------------------------------------------------------------
#define GATHER8(C, HB)                                                        \
  if ((C) < ncw) {                                                            \
    a0 = fmaf(vv[(C)][0], (HB)[ii[(C)][0]], a0);                              \
    a1 = fmaf(vv[(C)][1], (HB)[ii[(C)][1]], a1);                              \
    a2 = fmaf(vv[(C)][2], (HB)[ii[(C)][2]], a2);                              \
    a3 = fmaf(vv[(C)][3], (HB)[ii[(C)][3]], a3);                              \
    a0 = fmaf(vv[(C)][4], (HB)[ii[(C)][4]], a0);                              \
    a1 = fmaf(vv[(C)][5], (HB)[ii[(C)][5]], a1);                              \
    a2 = fmaf(vv[(C)][6], (HB)[ii[(C)][6]], a2);                              \
    a3 = fmaf(vv[(C)][7], (HB)[ii[(C)][7]], a3);                              \
  }

#define STEP(PAR, T)                                                          \
  {                                                                           \
    if ((T) > 0 && tid < OUTD) {                                              \
      float s = bia;                                                          \
      _Pragma("unroll")                                                       \
      for (int w = 0; w < 16; ++w) s += wpart[(PAR) ^ 1][w][tid];             \
      out[((size_t)b * SEQ + ((T) - 1)) * OUTD + tid] = s;                    \
    }                                                                         \
    if (tid >= 64 && tid < 68 && (T) + 1 < SEQ)                               \
      xbuf[(PAR) ^ 1][tid - 64] =                                             \
          ((const float4*)(xrow + (size_t)((T) + 1) * INPD))[tid - 64];       \
    const float4 xa = xbuf[PAR][0], xbv = xbuf[PAR][1];                       \
    const float4 xc = xbuf[PAR][2], xd  = xbuf[PAR][3];                       \
    float a0 = 0.f, a1 = 0.f, a2 = 0.f, a3 = 0.f;                             \
    a0 = fmaf(xa.x, w0.x, a0); a1 = fmaf(xa.y, w0.y, a1);                     \
    a2 = fmaf(xa.z, w0.z, a2); a3 = fmaf(xa.w, w0.w, a3);                     \
    a0 = fmaf(xbv.x, w1.x, a0); a1 = fmaf(xbv.y, w1.y, a1);                   \
    a2 = fmaf(xbv.z, w1.z, a2); a3 = fmaf(xbv.w, w1.w, a3);                   \
    a0 = fmaf(xc.x, w2.x, a0); a1 = fmaf(xc.y, w2.y, a1);                     \
    a2 = fmaf(xc.z, w2.z, a2); a3 = fmaf(xc.w, w2.w, a3);                     \
    a0 = fmaf(xd.x, w3.x, a0); a1 = fmaf(xd.y, w3.y, a1);                     \
    a2 = fmaf(xd.z, w3.z, a2); a3 = fmaf(xd.w, w3.w, a3);                     \
    const float* hb = &hbuf[PAR][0];                                          \
    _Pragma("unroll")                                                         \
    for (int c = 0; c < NCMAX; ++c) { GATHER8(c, hb) }                        \
    const float acc = (a0 + a1) + (a2 + a3);                                  \
    const float e   = exp2f(acc * 2.885390081777927f);                        \
    const float th  = 1.0f - 2.0f * __builtin_amdgcn_rcpf(e + 1.0f);          \
    const float hn  = fmaf(0.7f, th, 0.3f * hreg);                            \
    hreg = hn;                                                                \
    hbuf[(PAR) ^ 1][row] = hn;                                                \
    float po[OUTD];                                                           \
    _Pragma("unroll")                                                         \
    for (int o = 0; o < OUTD; ++o) po[o] = hn * wout[o];                      \
    _Pragma("unroll")                                                         \
    for (int d2 = 1; d2 < 64; d2 <<= 1) {                                     \
      _Pragma("unroll")                                                       \
      for (int o = 0; o < OUTD; ++o) po[o] += __shfl_xor(po[o], d2);          \
    }                                                                         \
    if (lane == 0) {                                                          \
      _Pragma("unroll")                                                       \
      for (int o = 0; o < OUTD; ++o) wpart[PAR][wave][o] = po[o];             \
    }                                                                         \
    __syncthreads();                                                          \
  }

__global__ __launch_bounds__(1024) void esn_scan(
    const float* __restrict__ x, const float* __restrict__ state,
    const float* __restrict__ Win, const float* __restrict__ Woutw,
    const float* __restrict__ Woutb,
    const uint32_t* __restrict__ idx, const float* __restrict__ val,
    const uint32_t* __restrict__ perm, const uint32_t* __restrict__ wnc,
    float* __restrict__ out) {
  __shared__ float  hbuf[2][RES];
  __shared__ float4 xbuf[2][INPD / 4];
  __shared__ float  wpart[2][16][OUTD];

  const int b    = blockIdx.x;
  const int tid  = threadIdx.x;
  const int wave = tid >> 6;
  const int lane = tid & 63;
  const int row  = (int)perm[tid];
  const int ncw  = (int)__builtin_amdgcn_readfirstlane(wnc[wave]);

  const float4* winp = (const float4*)(Win + (size_t)row * INPD);
  const float4 w0 = winp[0], w1 = winp[1], w2 = winp[2], w3 = winp[3];
  float wout[OUTD];
#pragma unroll
  for (int o = 0; o < OUTD; ++o) wout[o] = Woutw[o * RES + row];
  const float bia = (tid < OUTD) ? Woutb[tid] : 0.0f;

  float hreg = state[(size_t)b * RES + row];
  hbuf[0][row] = hreg;

  // load resident matrix into registers (compile-time indices only)
  uint32_t ii[NCMAX][8];
  float    vv[NCMAX][8];
#pragma unroll
  for (int c = 0; c < NCMAX; ++c) {
    if (c < ncw) {
      const uint4*  ip4 = (const uint4*)(idx + (size_t)c * (RES * 8) + (size_t)tid * 8);
      const float4* vp4 = (const float4*)(val + (size_t)c * (RES * 8) + (size_t)tid * 8);
      const uint4  ia = ip4[0], ib2 = ip4[1];
      const float4 va = vp4[0], vb2 = vp4[1];
      ii[c][0] = ia.x;  ii[c][1] = ia.y;  ii[c][2] = ia.z;  ii[c][3] = ia.w;
      ii[c][4] = ib2.x; ii[c][5] = ib2.y; ii[c][6] = ib2.z; ii[c][7] = ib2.w;
      vv[c][0] = va.x;  vv[c][1] = va.y;  vv[c][2] = va.z;  vv[c][3] = va.w;
      vv[c][4] = vb2.x; vv[c][5] = vb2.y; vv[c][6] = vb2.z; vv[c][7] = vb2.w;
    }
  }

  const float* xrow = x + (size_t)b * SEQ * INPD;
  if (tid < INPD / 4) xbuf[0][tid] = ((const float4*)xrow)[tid];
  float* finals = out + (size_t)BATCH * SEQ * OUTD;
  __syncthreads();

  for (int t = 0; t < SEQ; t += 2) {
    STEP(0, t)
    STEP(1, t + 1)
  }

  // outputs for t = SEQ-1 (par of 4095 is 1 -> wpart[1])
  if (tid < OUTD) {
    float s = bia;
#pragma unroll
    for (int w = 0; w < 16; ++w) s += wpart[1][w][tid];
    out[((size_t)b * SEQ + (SEQ - 1)) * OUTD + tid] = s;
  }
  finals[(size_t)b * RES + row] = hreg;
}

// ---------------------------------------------------------------------------
extern "C" void kernel_launch(void* const* d_in, const int* in_sizes, int n_in,
                              void* d_out, int out_size, void* d_ws, size_t ws_size,
                              hipStream_t stream) {
  const float* x     = (const float*)d_in[0];
  const float* state = (const float*)d_in[1];
  const float* Win   = (const float*)d_in[2];
  const float* Wres  = (const float*)d_in[3];
  const float* Woutw = (const float*)d_in[4];
  const float* Woutb = (const float*)d_in[5];
  float* out = (float*)d_out;

  uint8_t*  ws   = (uint8_t*)d_ws;
  uint32_t* idx  = (uint32_t*)ws;
  float*    val  = (float*)(ws + IDX_BYTES);
  uint32_t* eff  = (uint32_t*)(ws + 2 * IDX_BYTES);
  uint32_t* perm = (uint32_t*)(ws + 2 * IDX_BYTES + 4096);
  uint32_t* wnc  = (uint32_t*)(ws + 2 * IDX_BYTES + 8192);

  esn_count<<<RES, 32, 0, stream>>>(Wres, eff);
  esn_sort<<<1, RES, 0, stream>>>(eff, perm, wnc);
  esn_pack<<<RES, 32, 0, stream>>>(Wres, perm, idx, val);
  esn_scan<<<BATCH, RES, 0, stream>>>(x, state, Win, Woutw, Woutb,
                                      idx, val, perm, wnc, out);
}

// Round 3
// 35403.732 us; speedup vs baseline: 2.6056x; 2.6056x over previous
//
#include <hip/hip_runtime.h>
#include <stdint.h>

#define RES    1024
#define INPD   16
#define OUTD   8
#define BATCH  32
#define SEQ    4096
#define COLCAP 192            // padded max nnz per row (mean ~102)
#define NCHUNK (COLCAP / 8)
#define GROUP  4              // blocks (CUs) per batch element
#define SLICE  (RES / GROUP)  // 256 rows per block
#define NBLK   (BATCH * GROUP)

// ws layout:
//   idx: uint32 [NCHUNK][1024][8]
//   val: float  [NCHUNK][1024][8]
//   nnz: uint32 [1024]
//   cnt: uint32 [NBLK]            per-block monotonic step counter
//   pub: float  [2][BATCH][RES]   parity-double-buffered h slices
#define IDX_BYTES ((size_t)NCHUNK * RES * 8 * 4)   // 786432

// ---------------------------------------------------------------------------
// Preprocess (round-1, known good): compact each row of W_res into the
// chunked [chunk][row][8] layout. One wave per row.
// ---------------------------------------------------------------------------
__global__ __launch_bounds__(64) void esn_prep(const float* __restrict__ W,
                                               uint32_t* __restrict__ idx,
                                               float* __restrict__ val,
                                               uint32_t* __restrict__ nnz) {
  const int r    = blockIdx.x;
  const int lane = threadIdx.x;
  const float* row = W + (size_t)r * RES;

  uint32_t base = 0;
  for (int c = 0; c < RES / 64; ++c) {
    float v = row[c * 64 + lane];
    unsigned long long m = __ballot(v != 0.0f);
    uint32_t pos = (uint32_t)__popcll(m & ((1ull << lane) - 1ull));
    if (v != 0.0f) {
      uint32_t n = base + pos;
      if (n < COLCAP) {
        uint32_t off = (n >> 3) * (RES * 8) + (uint32_t)r * 8 + (n & 7u);
        idx[off] = (uint32_t)(c * 64 + lane);
        val[off] = v;
      }
    }
    base += (uint32_t)__popcll(m);
  }
  for (uint32_t n = base + (uint32_t)lane; n < COLCAP; n += 64) {
    uint32_t off = (n >> 3) * (RES * 8) + (uint32_t)r * 8 + (n & 7u);
    idx[off] = 0;
    val[off] = 0.0f;
  }
  if (lane == 0) nnz[r] = (base < COLCAP) ? base : (uint32_t)COLCAP;
}

// zero the handshake counters (every launch: harness poisons ws with 0xAA)
__global__ void esn_init(uint32_t* __restrict__ cnt) {
  if (threadIdx.x < NBLK) cnt[threadIdx.x] = 0;
}

// ---------------------------------------------------------------------------
// Scan: 4 blocks cooperate per batch element. Each block owns 256 rows,
// keeps the FULL h in its LDS (peer slices arrive via L2 each step).
// Per step: gather+FMA -> combine/tanh -> publish+flag -> spin -> copy-in.
// ---------------------------------------------------------------------------
__global__ __launch_bounds__(1024) void esn_scan(
    const float* __restrict__ x, const float* __restrict__ state,
    const float* __restrict__ Win, const float* __restrict__ Woutw,
    const float* __restrict__ Woutb,
    const uint32_t* __restrict__ idx, const float* __restrict__ val,
    const uint32_t* __restrict__ nnz,
    uint32_t* __restrict__ cnt, float* __restrict__ pub,
    float* __restrict__ out) {
  __shared__ float hbuf[2][RES];
  __shared__ __align__(16) float psum[SLICE][GROUP];
  __shared__ float4 xbuf[2][INPD / 4];

  const int bid  = blockIdx.x;
  const int grp  = bid >> 2;            // batch element
  const int role = bid & (GROUP - 1);   // which row-slice we own
  const int tid  = threadIdx.x;
  const int rloc = tid & (SLICE - 1);   // 0..255
  const int seg  = tid >> 8;            // 0..3: quarter of the row's chunks
  const int row  = role * SLICE + rloc;
  const int wave = tid >> 6;
  const int lane = tid & 63;

  // output-projection weights: wave w handles output o=w, 16-col slice/lane
  float wo[16];
#pragma unroll
  for (int j = 0; j < 16; ++j)
    wo[j] = (wave < OUTD) ? Woutw[wave * RES + lane + 64 * j] : 0.0f;
  const float bw = (wave < OUTD) ? Woutb[wave] : 0.0f;

  // input-projection weights: this seg's quarter of Win[row,:]
  const float4 w4 = ((const float4*)(Win + (size_t)row * INPD))[seg];

  hbuf[0][tid] = state[(size_t)grp * RES + tid];
  const float* xr = x + (size_t)grp * SEQ * INPD;
  if (tid < INPD / 4) xbuf[0][tid] = ((const float4*)xr)[tid];
  const int nc = (int)((nnz[row] + 7u) >> 3);
  __syncthreads();

  for (int t = 0; t < SEQ; ++t) {
    const int par = t & 1;
    const float* hc = hbuf[par];                       // h(t), full vector
    float* ppub = pub + ((size_t)(par ^ 1) * BATCH + grp) * RES;

    // stage x_{t+1}
    if (tid < INPD / 4 && t + 1 < SEQ)
      xbuf[par ^ 1][tid] = ((const float4*)(xr + (size_t)(t + 1) * INPD))[tid];

    // output projection for step t-1 (rotating role; 8 waves, 1 output each)
    if (t > 0 && role == ((t - 1) & 3) && wave < OUTD) {
      float s = 0.0f;
#pragma unroll
      for (int j = 0; j < 16; ++j) s = fmaf(hc[lane + 64 * j], wo[j], s);
#pragma unroll
      for (int d = 1; d < 64; d <<= 1) s += __shfl_xor(s, d);
      if (lane == 0) out[((size_t)grp * SEQ + (t - 1)) * OUTD + wave] = s + bw;
    }

    // fused input projection (this seg's quarter)
    const float4 xv = xbuf[par][seg];
    float a0 = 0.f, a1 = 0.f, a2 = 0.f, a3 = 0.f;
    a0 = fmaf(xv.x, w4.x, a0); a1 = fmaf(xv.y, w4.y, a1);
    a2 = fmaf(xv.z, w4.z, a2); a3 = fmaf(xv.w, w4.w, a3);

    // sparse gather over this seg's chunks of the row
    for (int c = seg; c < nc; c += GROUP) {
      const size_t base = ((size_t)c * RES + row) * 8;
      const uint4  ia = *(const uint4*)(idx + base);
      const uint4  ib = *(const uint4*)(idx + base + 4);
      const float4 va = *(const float4*)(val + base);
      const float4 vb = *(const float4*)(val + base + 4);
      a0 = fmaf(va.x, hc[ia.x], a0);
      a1 = fmaf(va.y, hc[ia.y], a1);
      a2 = fmaf(va.z, hc[ia.z], a2);
      a3 = fmaf(va.w, hc[ia.w], a3);
      a0 = fmaf(vb.x, hc[ib.x], a0);
      a1 = fmaf(vb.y, hc[ib.y], a1);
      a2 = fmaf(vb.z, hc[ib.z], a2);
      a3 = fmaf(vb.w, hc[ib.w], a3);
    }
    psum[rloc][seg] = (a0 + a1) + (a2 + a3);
    __syncthreads();                                   // b1: psum ready

    // combine 4 segs, tanh, leak; write own slice to LDS + publish to L2
    if (tid < SLICE) {
      const float4 p = *(const float4*)&psum[tid][0];
      const float acc = (p.x + p.y) + (p.z + p.w);
      const float e  = exp2f(acc * 2.885390081777927f);  // 2*log2(e)
      const float th = 1.0f - 2.0f * __builtin_amdgcn_rcpf(e + 1.0f);
      const int r = role * SLICE + tid;
      const float hn = fmaf(0.7f, th, 0.3f * hc[r]);
      hbuf[par ^ 1][r] = hn;
      ppub[r] = hn;
    }
    __syncthreads();                                   // b2: publish issued

    if (tid == 0) {
      __threadfence();                                 // device-scope release
      __hip_atomic_store(&cnt[bid], (uint32_t)(t + 1), __ATOMIC_RELEASE,
                         __HIP_MEMORY_SCOPE_AGENT);
    }
    if (tid < GROUP && tid != role) {                  // spin on 3 peers
      const uint32_t want = (uint32_t)(t + 1);
      while (__hip_atomic_load(&cnt[grp * GROUP + tid], __ATOMIC_ACQUIRE,
                               __HIP_MEMORY_SCOPE_AGENT) < want)
        __builtin_amdgcn_s_sleep(1);
    }
    __syncthreads();                                   // b3: peers arrived

    // copy peer slices into next h buffer
    if ((tid >> 8) != role) hbuf[par ^ 1][tid] = ppub[tid];
    __syncthreads();                                   // b4: h(t+1) complete
  }

  // tail: output for t = SEQ-1 and final state (h(SEQ) lives in hbuf[0])
  if (role == 0) {
    if (wave < OUTD) {
      float s = 0.0f;
#pragma unroll
      for (int j = 0; j < 16; ++j) s = fmaf(hbuf[0][lane + 64 * j], wo[j], s);
#pragma unroll
      for (int d = 1; d < 64; d <<= 1) s += __shfl_xor(s, d);
      if (lane == 0) out[((size_t)grp * SEQ + (SEQ - 1)) * OUTD + wave] = s + bw;
    }
    float* finals = out + (size_t)BATCH * SEQ * OUTD;
    finals[(size_t)grp * RES + tid] = hbuf[0][tid];
  }
}

// ---------------------------------------------------------------------------
extern "C" void kernel_launch(void* const* d_in, const int* in_sizes, int n_in,
                              void* d_out, int out_size, void* d_ws, size_t ws_size,
                              hipStream_t stream) {
  const float* x     = (const float*)d_in[0];
  const float* state = (const float*)d_in[1];
  const float* Win   = (const float*)d_in[2];
  const float* Wres  = (const float*)d_in[3];
  const float* Woutw = (const float*)d_in[4];
  const float* Woutb = (const float*)d_in[5];
  float* out = (float*)d_out;

  uint8_t*  ws  = (uint8_t*)d_ws;
  uint32_t* idx = (uint32_t*)ws;
  float*    val = (float*)(ws + IDX_BYTES);
  uint32_t* nnz = (uint32_t*)(ws + 2 * IDX_BYTES);
  uint32_t* cnt = (uint32_t*)(ws + 2 * IDX_BYTES + 4096);
  float*    pub = (float*)(ws + 2 * IDX_BYTES + 4096 + 1024);

  esn_prep<<<RES, 64, 0, stream>>>(Wres, idx, val, nnz);
  esn_init<<<1, 128, 0, stream>>>(cnt);
  esn_scan<<<NBLK, RES, 0, stream>>>(x, state, Win, Woutw, Woutb,
                                     idx, val, nnz, cnt, pub, out);
}

// Round 4
// 19074.557 us; speedup vs baseline: 4.8363x; 1.8561x over previous
//
#include <hip/hip_runtime.h>
#include <stdint.h>

#define RES     1024
#define INPD    16
#define OUTD    8
#define BATCH   32
#define SEQ     4096
#define NCMAX   24             // capacity: 24 chunks * 8 = 192 slots/row (eff max ~165)
#define PASSPAD 3              // first 3 passes per bank are exact Latin-square

// ws layout:
//   mat:  u32 [NCMAX][1024][8]  packed (col<<18)|bf16(val); pads have val=0
//   eff:  u32 [1024]            padded row length
//   perm: u32 [1024]            rows sorted ascending by eff
//   wnc:  u32 [16]              per-wave chunk count
#define MAT_BYTES ((size_t)NCMAX * RES * 8 * 4)   // 786432

// ---------------------------------------------------------------------------
// Pass 1: padded row length = 96 + sum_b max(cnt_bank - 3, 0)
// ---------------------------------------------------------------------------
__global__ __launch_bounds__(32) void esn_count(const float* __restrict__ W,
                                                uint32_t* __restrict__ eff) {
  const int r = blockIdx.x, b = threadIdx.x;   // b = bank 0..31
  const float* row = W + (size_t)r * RES;
  int n = 0;
  for (int k = 0; k < 32; ++k) n += (row[b + 32 * k] != 0.0f) ? 1 : 0;
  int t3 = (n > PASSPAD) ? (n - PASSPAD) : 0;
  for (int o = 16; o; o >>= 1) t3 += __shfl_down(t3, o, 32);
  if (b == 0) eff[r] = (uint32_t)(PASSPAD * 32 + t3);
}

// ---------------------------------------------------------------------------
// Pass 2: bitonic sort rows by eff ASCENDING -> perm (waves 8..15 get the
// long rows; waves 0..7 get short rows + projection duty); per-wave chunks.
// ---------------------------------------------------------------------------
__global__ __launch_bounds__(1024) void esn_sort(const uint32_t* __restrict__ eff,
                                                 uint32_t* __restrict__ perm,
                                                 uint32_t* __restrict__ wnc) {
  __shared__ uint32_t key[RES];
  const int tid = threadIdx.x;
  key[tid] = (eff[tid] << 10) | (uint32_t)tid;
  __syncthreads();
  for (int len = 2; len <= RES; len <<= 1) {
    for (int s = len >> 1; s > 0; s >>= 1) {
      const int j = tid ^ s;
      if (j > tid) {
        const uint32_t a = key[tid], c = key[j];
        const bool up = ((tid & len) == 0);
        if ((a > c) == up) { key[tid] = c; key[j] = a; }
      }
      __syncthreads();
    }
  }
  const uint32_t k = key[tid];                  // ascending
  perm[tid] = k & 1023u;
  if ((tid & 63) == 63) {                       // max eff in this wave
    uint32_t c = ((k >> 10) + 7u) >> 3;
    wnc[tid >> 6] = (c < (uint32_t)NCMAX) ? c : (uint32_t)NCMAX;
  }
}

// ---------------------------------------------------------------------------
// Pass 3: pack row perm[p] in rotated bank-scheduled order (round-2 proven
// rank formula). Slot rank r in the Latin region reads bank (rot+(r&31))&31
// for every lane -> exactly 2 lanes/bank = conflict-free. Pads are
// bank-spread dummy columns with bf16 value 0.
// ---------------------------------------------------------------------------
__global__ __launch_bounds__(32) void esn_pack(const float* __restrict__ W,
                                               const uint32_t* __restrict__ perm,
                                               uint32_t* __restrict__ mato) {
  const int p = blockIdx.x;      // sorted position == scan tid
  const int b = threadIdx.x;     // bank 0..31
  __shared__ float    vls[32][16];
  __shared__ uint16_t cls[32][16];
  __shared__ int      cnt[32];
  __shared__ uint32_t rr;
  if (b == 0) rr = perm[p];
  __syncthreads();
  const float* row = W + (size_t)rr * RES;

  int n = 0;
  for (int k = 0; k < 32; ++k) {
    const float v = row[b + 32 * k];
    if (v != 0.0f && n < 16) { vls[b][n] = v; cls[b][n] = (uint16_t)(b + 32 * k); ++n; }
  }
  cnt[b] = n;
  const int rot = p & 31;
  // pad-fill whole capacity with bank-spread zero-valued entries
  for (int e = b; e < NCMAX * 8; e += 32) {
    const uint32_t padcol = (uint32_t)((rot + (e & 31)) & 31);
    mato[(size_t)(e >> 3) * (RES * 8) + (size_t)p * 8 + (e & 7)] = padcol << 18;
  }
  __syncthreads();

  const int myord = (b - rot) & 31;
  for (int k2 = 0; k2 < n; ++k2) {
    int rank;
    if (k2 < PASSPAD) {
      rank = k2 * 32 + myord;
    } else {
      rank = PASSPAD * 32;
      const int kp = k2 - PASSPAD;
      for (int b2 = 0; b2 < 32; ++b2) {
        int cp = cnt[b2] - PASSPAD; cp = (cp > 0) ? cp : 0;
        const int ord = (b2 - rot) & 31;
        const int lim = kp + ((ord < myord) ? 1 : 0);
        rank += (cp < lim) ? cp : lim;
      }
    }
    if (rank < NCMAX * 8) {
      const uint32_t u  = __float_as_uint(vls[b][k2]);
      const uint32_t bf = (u + 0x7FFFu + ((u >> 16) & 1u)) >> 16;   // RNE bf16
      mato[(size_t)(rank >> 3) * (RES * 8) + (size_t)p * 8 + (rank & 7)] =
          ((uint32_t)cls[b][k2] << 18) | bf;
    }
  }
}

// ---------------------------------------------------------------------------
// Scan: one block per batch. Packed-dword stream with depth-1 prefetch;
// conflict-free LDS gathers; 8 projection waves; one barrier per step.
// ---------------------------------------------------------------------------
#define GATHER8(QA, QB)                                                       \
  a0 = fmaf(__uint_as_float((QA).x << 16), hc[(QA).x >> 18], a0);             \
  a1 = fmaf(__uint_as_float((QA).y << 16), hc[(QA).y >> 18], a1);             \
  a2 = fmaf(__uint_as_float((QA).z << 16), hc[(QA).z >> 18], a2);             \
  a3 = fmaf(__uint_as_float((QA).w << 16), hc[(QA).w >> 18], a3);             \
  a0 = fmaf(__uint_as_float((QB).x << 16), hc[(QB).x >> 18], a0);             \
  a1 = fmaf(__uint_as_float((QB).y << 16), hc[(QB).y >> 18], a1);             \
  a2 = fmaf(__uint_as_float((QB).z << 16), hc[(QB).z >> 18], a2);             \
  a3 = fmaf(__uint_as_float((QB).w << 16), hc[(QB).w >> 18], a3);

__global__ __launch_bounds__(1024) void esn_scan(
    const float* __restrict__ x, const float* __restrict__ state,
    const float* __restrict__ Win, const float* __restrict__ Woutw,
    const float* __restrict__ Woutb,
    const uint32_t* __restrict__ mat, const uint32_t* __restrict__ perm,
    const uint32_t* __restrict__ wnc,
    float* __restrict__ out) {
  __shared__ float  hbuf[2][RES];
  __shared__ float4 xbuf[2][INPD / 4];

  const int b    = blockIdx.x;
  const int tid  = threadIdx.x;
  const int wave = tid >> 6;
  const int lane = tid & 63;
  const int row  = (int)perm[tid];
  const int ncw  = (int)__builtin_amdgcn_readfirstlane(wnc[wave]);

  const float4* winp = (const float4*)(Win + (size_t)row * INPD);
  const float4 w0 = winp[0], w1 = winp[1], w2 = winp[2], w3 = winp[3];

  // projection weights (waves 0..7 only; wave o owns output o)
  float wo[16];
  const float* wor = Woutw + (size_t)wave * RES;
#pragma unroll
  for (int j = 0; j < 16; ++j) wo[j] = (wave < OUTD) ? wor[lane + 64 * j] : 0.0f;
  const float bw = (wave < OUTD) ? Woutb[wave] : 0.0f;

  float hreg = state[(size_t)b * RES + row];
  hbuf[0][row] = hreg;
  const float* xr = x + (size_t)b * SEQ * INPD;
  if (tid < INPD / 4) xbuf[0][tid] = ((const float4*)xr)[tid];
  __syncthreads();

  const uint32_t* mp = mat + (size_t)tid * 8;
  float* finals = out + (size_t)BATCH * SEQ * OUTD;

  for (int t = 0; t < SEQ; ++t) {
    const int par = t & 1;
    const float* hc = hbuf[par];                 // states[t-1] (state at t=0)

    // output projection for step t-1 (waves 0..7, one output each)
    if (t > 0 && wave < OUTD) {
      float s = 0.0f;
#pragma unroll
      for (int j = 0; j < 16; ++j) s = fmaf(hc[lane + 64 * j], wo[j], s);
#pragma unroll
      for (int d = 1; d < 64; d <<= 1) s += __shfl_xor(s, d);
      if (lane == 0) out[((size_t)b * SEQ + (t - 1)) * OUTD + wave] = s + bw;
    }
    // stage x_{t+1}
    if (tid < INPD / 4 && t + 1 < SEQ)
      xbuf[par ^ 1][tid] = ((const float4*)(xr + (size_t)(t + 1) * INPD))[tid];

    // input projection
    const float4 xa = xbuf[par][0], xbv = xbuf[par][1];
    const float4 xc = xbuf[par][2], xd  = xbuf[par][3];
    float a0 = 0.f, a1 = 0.f, a2 = 0.f, a3 = 0.f;
    a0 = fmaf(xa.x, w0.x, a0);  a1 = fmaf(xa.y, w0.y, a1);
    a2 = fmaf(xa.z, w0.z, a2);  a3 = fmaf(xa.w, w0.w, a3);
    a0 = fmaf(xbv.x, w1.x, a0); a1 = fmaf(xbv.y, w1.y, a1);
    a2 = fmaf(xbv.z, w1.z, a2); a3 = fmaf(xbv.w, w1.w, a3);
    a0 = fmaf(xc.x, w2.x, a0);  a1 = fmaf(xc.y, w2.y, a1);
    a2 = fmaf(xc.z, w2.z, a2);  a3 = fmaf(xc.w, w2.w, a3);
    a0 = fmaf(xd.x, w3.x, a0);  a1 = fmaf(xd.y, w3.y, a1);
    a2 = fmaf(xd.z, w3.z, a2);  a3 = fmaf(xd.w, w3.w, a3);

    // sparse gather, depth-1 prefetched packed stream
    uint4 qa = *(const uint4*)mp;
    uint4 qb = *(const uint4*)(mp + 4);
    for (int c = 0; c < ncw - 1; ++c) {
      const uint32_t* cpn = mp + (size_t)(c + 1) * (RES * 8);
      const uint4 na = *(const uint4*)cpn;
      const uint4 nb = *(const uint4*)(cpn + 4);
      GATHER8(qa, qb)
      qa = na; qb = nb;
    }
    GATHER8(qa, qb)

    const float acc = (a0 + a1) + (a2 + a3);
    const float e   = exp2f(acc * 2.885390081777927f);        // 2*log2(e)*acc
    const float th  = 1.0f - 2.0f * __builtin_amdgcn_rcpf(e + 1.0f);
    const float hn  = fmaf(0.7f, th, 0.3f * hreg);
    hreg = hn;
    hbuf[par ^ 1][row] = hn;
    __syncthreads();
  }

  // out[SEQ-1] from hbuf[0] (= states[SEQ-1]); final state
  if (wave < OUTD) {
    float s = 0.0f;
#pragma unroll
    for (int j = 0; j < 16; ++j) s = fmaf(hbuf[0][lane + 64 * j], wo[j], s);
#pragma unroll
    for (int d = 1; d < 64; d <<= 1) s += __shfl_xor(s, d);
    if (lane == 0) out[((size_t)b * SEQ + (SEQ - 1)) * OUTD + wave] = s + bw;
  }
  finals[(size_t)b * RES + row] = hreg;
}

// ---------------------------------------------------------------------------
extern "C" void kernel_launch(void* const* d_in, const int* in_sizes, int n_in,
                              void* d_out, int out_size, void* d_ws, size_t ws_size,
                              hipStream_t stream) {
  const float* x     = (const float*)d_in[0];
  const float* state = (const float*)d_in[1];
  const float* Win   = (const float*)d_in[2];
  const float* Wres  = (const float*)d_in[3];
  const float* Woutw = (const float*)d_in[4];
  const float* Woutb = (const float*)d_in[5];
  float* out = (float*)d_out;

  uint8_t*  ws   = (uint8_t*)d_ws;
  uint32_t* mat  = (uint32_t*)ws;
  uint32_t* eff  = (uint32_t*)(ws + MAT_BYTES);
  uint32_t* perm = (uint32_t*)(ws + MAT_BYTES + 4096);
  uint32_t* wnc  = (uint32_t*)(ws + MAT_BYTES + 8192);

  esn_count<<<RES, 32, 0, stream>>>(Wres, eff);
  esn_sort<<<1, RES, 0, stream>>>(eff, perm, wnc);
  esn_pack<<<RES, 32, 0, stream>>>(Wres, perm, mat);
  esn_scan<<<BATCH, RES, 0, stream>>>(x, state, Win, Woutw, Woutb,
                                      mat, perm, wnc, out);
}